// Round 2
// baseline (1370.994 us; speedup 1.0000x reference)
//
#include <hip/hip_runtime.h>

// DecoderLayer (eval): SA(causal) -> +res -> LN1 -> CA -> +res -> LN2 -> FFN -> +res -> LN3
// Pure fp32 (reference-accurate; no fp32 MFMA on CDNA4 so GEMMs/attention are VALU-bound).
// Masks handled structurally: src_mask all-ones (no-op), tgt_mask causal tril.
//
// Round-1 design:
//  - GEMM: 64x64 tile, BK=32, 256 thr, 4x4 microtile, A staged transposed (pad 68),
//    all LDS traffic as b128, fused bias/residual/ReLU, optional [B,H,S,dk] output.
//  - Attention: GEMM-shaped flash. 64 queries/block, 4 waves. Q^T,K^T,V,P^T tiles in LDS
//    (68-float stride), 4x4 microtile QK^T and PV, online softmax with 16-lane shfl
//    reductions. No SxS materialization.
//  - LayerNorm: 1 wave/row, float4 loads.

#define D_MODEL 512
#define NHEAD 8
#define DK 64
#define SEQ 2048
#define MTOK 4096  // B*S
#define DFF 2048

// ---------------------------------------------------------------------------
// GEMM: out = A[M,K] @ W[K,N] + bias (+ res) (ReLU optional).
// HEADS: write out in [B,H,S,dk] layout (N must be 512).
template<bool HEADS, bool RELU>
__global__ __launch_bounds__(256)
void gemm_kernel(const float* __restrict__ A, const float* __restrict__ W,
                 const float* __restrict__ bias, const float* __restrict__ res,
                 float* __restrict__ out, int M, int N, int K) {
  __shared__ float As[32][68];  // [k][m] transposed, padded (68*4B % 16 == 0)
  __shared__ float Bs[32][64];  // [k][n] natural
  const int tid = threadIdx.x;
  const int bm = blockIdx.x, bn = blockIdx.y;
  const int tn = tid & 15, tm = tid >> 4;   // microtile coords: rows 4*tm, cols 4*tn
  // staging coords
  const int ar = tid >> 3;              // 0..31  (A row, +32 on second load)
  const int ak = (tid & 7) << 2;        // 0..28  (A k-group of 4)
  const int bk = tid >> 4;              // 0..15  (B k-row, +16 on second load)
  const int bc = (tid & 15) << 2;       // B col group of 4
  const float* Ap = A + (long)(bm * 64 + ar) * K + ak;
  const float* Wp = W + (long)bk * N + bn * 64 + bc;
  float acc[4][4] = {};
  for (int k0 = 0; k0 < K; k0 += 32) {
    float4 a0 = *(const float4*)(Ap + k0);
    float4 a1 = *(const float4*)(Ap + 32 * (long)K + k0);
    float4 b0 = *(const float4*)(Wp + (long)k0 * N);
    float4 b1 = *(const float4*)(Wp + (long)(k0 + 16) * N);
    __syncthreads();  // previous iteration's LDS reads complete
    As[ak + 0][ar] = a0.x; As[ak + 1][ar] = a0.y; As[ak + 2][ar] = a0.z; As[ak + 3][ar] = a0.w;
    As[ak + 0][ar + 32] = a1.x; As[ak + 1][ar + 32] = a1.y; As[ak + 2][ar + 32] = a1.z; As[ak + 3][ar + 32] = a1.w;
    *(float4*)&Bs[bk][bc] = b0;
    *(float4*)&Bs[bk + 16][bc] = b1;
    __syncthreads();
#pragma unroll
    for (int kk = 0; kk < 32; kk++) {
      float4 a4 = *(const float4*)&As[kk][tm * 4];
      float4 b4 = *(const float4*)&Bs[kk][tn * 4];
      float a[4] = {a4.x, a4.y, a4.z, a4.w};
      float b[4] = {b4.x, b4.y, b4.z, b4.w};
#pragma unroll
      for (int i = 0; i < 4; i++)
#pragma unroll
        for (int j = 0; j < 4; j++) acc[i][j] = fmaf(a[i], b[j], acc[i][j]);
    }
  }
  const int c0 = bn * 64 + tn * 4;
  const float4 bv = *(const float4*)&bias[c0];
#pragma unroll
  for (int i = 0; i < 4; i++) {
    const int r = bm * 64 + tm * 4 + i;
    float4 v = make_float4(acc[i][0] + bv.x, acc[i][1] + bv.y,
                           acc[i][2] + bv.z, acc[i][3] + bv.w);
    if (res) {
      float4 rv = *(const float4*)&res[(long)r * N + c0];
      v.x += rv.x; v.y += rv.y; v.z += rv.z; v.w += rv.w;
    }
    if (RELU) {
      v.x = fmaxf(v.x, 0.f); v.y = fmaxf(v.y, 0.f);
      v.z = fmaxf(v.z, 0.f); v.w = fmaxf(v.w, 0.f);
    }
    if (HEADS) {
      const int b = r >> 11, s = r & (SEQ - 1);
      const int h = c0 >> 6, d = c0 & 63;
      *(float4*)&out[(((long)(b * NHEAD + h)) * SEQ + s) * DK + d] = v;
    } else {
      *(float4*)&out[(long)r * N + c0] = v;
    }
  }
}

// ---------------------------------------------------------------------------
// GEMM-shaped flash attention. Q,K,V in [B,H,S,dk]; O in [B,S,D_MODEL].
// Block: 256 thr, 64 query rows of one (b,h). grid = (S/64, B*H).
template<bool CAUSAL>
__global__ __launch_bounds__(256)
void attn_kernel(const float* __restrict__ Qg, const float* __restrict__ Kg,
                 const float* __restrict__ Vg, float* __restrict__ Og) {
  __shared__ float Qt[64][68];  // [d][q]  (pre-scaled by 1/8)
  __shared__ float Kt[64][68];  // [d][k]
  __shared__ float Vt[64][68];  // [k][d]
  __shared__ float Pt[64][68];  // [k][q]
  const int tid = threadIdx.x;
  const int qb = blockIdx.x;        // query tile
  const int bh = blockIdx.y;        // b*NHEAD + h
  const int tx = tid & 15, ty = tid >> 4;  // q rows 4*ty+i, k/d cols 4*tx+j
  const long base = (long)bh * SEQ * DK;

  // stage Q transposed + scaled (once)
#pragma unroll
  for (int it = 0; it < 4; it++) {
    const int idx = tid + it * 256;
    const int r = idx >> 4, dg = (idx & 15) << 2;
    float4 q = *(const float4*)&Qg[base + (long)(qb * 64 + r) * DK + dg];
    Qt[dg + 0][r] = q.x * 0.125f;
    Qt[dg + 1][r] = q.y * 0.125f;
    Qt[dg + 2][r] = q.z * 0.125f;
    Qt[dg + 3][r] = q.w * 0.125f;
  }

  float o[4][4] = {};
  float m[4] = {-1e30f, -1e30f, -1e30f, -1e30f};
  float l[4] = {};

  const int ntile = CAUSAL ? (qb + 1) : (SEQ / 64);
  for (int t = 0; t < ntile; t++) {
    const int k0 = t * 64;
    __syncthreads();  // prev PV reads of Vt/Pt done; Qt visible on t=0
#pragma unroll
    for (int it = 0; it < 4; it++) {
      const int idx = tid + it * 256;
      const int r = idx >> 4, dg = (idx & 15) << 2;
      float4 k = *(const float4*)&Kg[base + (long)(k0 + r) * DK + dg];
      float4 v = *(const float4*)&Vg[base + (long)(k0 + r) * DK + dg];
      Kt[dg + 0][r] = k.x; Kt[dg + 1][r] = k.y; Kt[dg + 2][r] = k.z; Kt[dg + 3][r] = k.w;
      *(float4*)&Vt[r][dg] = v;
    }
    __syncthreads();

    // S = (Q/8) @ K^T  (64x64, 4x4 per thread)
    float s[4][4] = {};
#pragma unroll
    for (int d = 0; d < 64; d++) {
      float4 qf = *(const float4*)&Qt[d][ty * 4];
      float4 kf = *(const float4*)&Kt[d][tx * 4];
      float a[4] = {qf.x, qf.y, qf.z, qf.w};
      float b[4] = {kf.x, kf.y, kf.z, kf.w};
#pragma unroll
      for (int i = 0; i < 4; i++)
#pragma unroll
        for (int j = 0; j < 4; j++) s[i][j] = fmaf(a[i], b[j], s[i][j]);
    }
    if (CAUSAL && k0 == qb * 64) {  // diagonal tile
#pragma unroll
      for (int i = 0; i < 4; i++)
#pragma unroll
        for (int j = 0; j < 4; j++)
          if (k0 + tx * 4 + j > qb * 64 + ty * 4 + i) s[i][j] = -1e30f;
    }

    // online softmax (row stats across the 16 lanes sharing ty)
#pragma unroll
    for (int i = 0; i < 4; i++) {
      float mx = fmaxf(fmaxf(s[i][0], s[i][1]), fmaxf(s[i][2], s[i][3]));
#pragma unroll
      for (int off = 8; off > 0; off >>= 1) mx = fmaxf(mx, __shfl_xor(mx, off, 64));
      const float mnew = fmaxf(m[i], mx);
      const float corr = __expf(m[i] - mnew);
      m[i] = mnew;
      float ps = 0.f;
#pragma unroll
      for (int j = 0; j < 4; j++) { s[i][j] = __expf(s[i][j] - mnew); ps += s[i][j]; }
#pragma unroll
      for (int off = 8; off > 0; off >>= 1) ps += __shfl_xor(ps, off, 64);
      l[i] = l[i] * corr + ps;
#pragma unroll
      for (int j = 0; j < 4; j++) o[i][j] *= corr;
    }
    // stage P transposed: Pt[k][q]
#pragma unroll
    for (int i = 0; i < 4; i++)
#pragma unroll
      for (int j = 0; j < 4; j++) Pt[tx * 4 + j][ty * 4 + i] = s[i][j];
    __syncthreads();

    // O += P @ V  (contraction over this tile's 64 keys)
#pragma unroll
    for (int k = 0; k < 64; k++) {
      float4 pf = *(const float4*)&Pt[k][ty * 4];
      float4 vf = *(const float4*)&Vt[k][tx * 4];
      float a[4] = {pf.x, pf.y, pf.z, pf.w};
      float b[4] = {vf.x, vf.y, vf.z, vf.w};
#pragma unroll
      for (int i = 0; i < 4; i++)
#pragma unroll
        for (int j = 0; j < 4; j++) o[i][j] = fmaf(a[i], b[j], o[i][j]);
    }
  }

  const int b = bh >> 3, h = bh & 7;
#pragma unroll
  for (int i = 0; i < 4; i++) {
    const int q = qb * 64 + ty * 4 + i;
    const float rl = 1.f / l[i];
    float4 v = make_float4(o[i][0] * rl, o[i][1] * rl, o[i][2] * rl, o[i][3] * rl);
    *(float4*)&Og[((long)(b * SEQ + q)) * D_MODEL + h * DK + tx * 4] = v;
  }
}

// ---------------------------------------------------------------------------
// LayerNorm over last dim (512). One wave per row, 8 elems/lane.
__global__ __launch_bounds__(256)
void ln_kernel(const float* __restrict__ x, const float* __restrict__ g,
               const float* __restrict__ b, float* __restrict__ out) {
  const int row = blockIdx.x * 4 + (threadIdx.x >> 6);
  const int lane = threadIdx.x & 63;
  const float* xr = x + (long)row * D_MODEL;
  float4 v0 = *(const float4*)&xr[lane * 8];
  float4 v1 = *(const float4*)&xr[lane * 8 + 4];
  float xv[8] = {v0.x, v0.y, v0.z, v0.w, v1.x, v1.y, v1.z, v1.w};
  float s = 0.f, s2 = 0.f;
#pragma unroll
  for (int i = 0; i < 8; i++) { s += xv[i]; s2 = fmaf(xv[i], xv[i], s2); }
#pragma unroll
  for (int off = 32; off > 0; off >>= 1) {
    s += __shfl_xor(s, off, 64);
    s2 += __shfl_xor(s2, off, 64);
  }
  const float mu = s * (1.f / D_MODEL);
  const float var = fmaxf(s2 * (1.f / D_MODEL) - mu * mu, 0.f);
  const float rstd = rsqrtf(var + 1e-5f);
  float* orow = out + (long)row * D_MODEL;
#pragma unroll
  for (int i = 0; i < 8; i++) {
    const int c = lane * 8 + i;
    orow[c] = (xv[i] - mu) * rstd * g[c] + b[c];
  }
}

// ---------------------------------------------------------------------------
extern "C" void kernel_launch(void* const* d_in, const int* in_sizes, int n_in,
                              void* d_out, int out_size, void* d_ws, size_t ws_size,
                              hipStream_t stream) {
  const float* dec = (const float*)d_in[0];
  const float* enc = (const float*)d_in[1];
  // d_in[2] src_mask (all ones), d_in[3] tgt_mask (causal tril): structural.
  const float* sa_wq = (const float*)d_in[4];
  const float* sa_bq = (const float*)d_in[5];
  const float* sa_wk = (const float*)d_in[6];
  const float* sa_bk = (const float*)d_in[7];
  const float* sa_wv = (const float*)d_in[8];
  const float* sa_bv = (const float*)d_in[9];
  const float* sa_wo = (const float*)d_in[10];
  const float* sa_bo = (const float*)d_in[11];
  const float* ca_wq = (const float*)d_in[12];
  const float* ca_bq = (const float*)d_in[13];
  const float* ca_wk = (const float*)d_in[14];
  const float* ca_bk = (const float*)d_in[15];
  const float* ca_wv = (const float*)d_in[16];
  const float* ca_bv = (const float*)d_in[17];
  const float* ca_wo = (const float*)d_in[18];
  const float* ca_bo = (const float*)d_in[19];
  const float* ffn_w1 = (const float*)d_in[20];
  const float* ffn_b1 = (const float*)d_in[21];
  const float* ffn_w2 = (const float*)d_in[22];
  const float* ffn_b2 = (const float*)d_in[23];
  const float* ln1_g = (const float*)d_in[24];
  const float* ln1_b = (const float*)d_in[25];
  const float* ln2_g = (const float*)d_in[26];
  const float* ln2_b = (const float*)d_in[27];
  const float* ln3_g = (const float*)d_in[28];
  const float* ln3_b = (const float*)d_in[29];

  // workspace (floats): Q,K,V,AO,R,X1,X2 (2M each) + MID (8M) = 88 MB
  const long CH = (long)MTOK * D_MODEL;
  float* ws = (float*)d_ws;
  float* Q  = ws;
  float* Kb = ws + CH;
  float* Vb = ws + 2 * CH;
  float* AO = ws + 3 * CH;
  float* R  = ws + 4 * CH;
  float* X1 = ws + 5 * CH;
  float* X2 = ws + 6 * CH;
  float* MID = ws + 7 * CH;  // 4096 x 2048

  dim3 blk(256);
  dim3 g512(MTOK / 64, D_MODEL / 64);   // (64, 8)
  dim3 gff1(MTOK / 64, DFF / 64);       // (64, 32)
  dim3 gattn(SEQ / 64, 2 * NHEAD);      // (32, 16)

  // ---- self-attention ----
  gemm_kernel<true, false><<<g512, blk, 0, stream>>>(dec, sa_wq, sa_bq, nullptr, Q,  MTOK, D_MODEL, D_MODEL);
  gemm_kernel<true, false><<<g512, blk, 0, stream>>>(dec, sa_wk, sa_bk, nullptr, Kb, MTOK, D_MODEL, D_MODEL);
  gemm_kernel<true, false><<<g512, blk, 0, stream>>>(dec, sa_wv, sa_bv, nullptr, Vb, MTOK, D_MODEL, D_MODEL);
  attn_kernel<true><<<gattn, blk, 0, stream>>>(Q, Kb, Vb, AO);
  gemm_kernel<false, false><<<g512, blk, 0, stream>>>(AO, sa_wo, sa_bo, dec, R, MTOK, D_MODEL, D_MODEL);
  ln_kernel<<<MTOK / 4, blk, 0, stream>>>(R, ln1_g, ln1_b, X1);

  // ---- cross-attention ----
  gemm_kernel<true, false><<<g512, blk, 0, stream>>>(X1,  ca_wq, ca_bq, nullptr, Q,  MTOK, D_MODEL, D_MODEL);
  gemm_kernel<true, false><<<g512, blk, 0, stream>>>(enc, ca_wk, ca_bk, nullptr, Kb, MTOK, D_MODEL, D_MODEL);
  gemm_kernel<true, false><<<g512, blk, 0, stream>>>(enc, ca_wv, ca_bv, nullptr, Vb, MTOK, D_MODEL, D_MODEL);
  attn_kernel<false><<<gattn, blk, 0, stream>>>(Q, Kb, Vb, AO);
  gemm_kernel<false, false><<<g512, blk, 0, stream>>>(AO, ca_wo, ca_bo, X1, R, MTOK, D_MODEL, D_MODEL);
  ln_kernel<<<MTOK / 4, blk, 0, stream>>>(R, ln2_g, ln2_b, X2);

  // ---- FFN ----
  gemm_kernel<false, true><<<gff1, blk, 0, stream>>>(X2, ffn_w1, ffn_b1, nullptr, MID, MTOK, DFF, D_MODEL);
  gemm_kernel<false, false><<<g512, blk, 0, stream>>>(MID, ffn_w2, ffn_b2, X2, R, MTOK, D_MODEL, DFF);
  ln_kernel<<<MTOK / 4, blk, 0, stream>>>(R, ln3_g, ln3_b, (float*)d_out);
}

// Round 3
// 500.762 us; speedup vs baseline: 2.7378x; 2.7378x over previous
//
#include <hip/hip_runtime.h>

// DecoderLayer (eval): SA(causal) -> +res -> LN1 -> CA -> +res -> LN2 -> FFN -> +res -> LN3
// Round-2: bf16 MFMA everywhere matmul-shaped (16x16x32_bf16), fp32 accum,
// fp32 residuals/bias/LN/softmax state. Masks structural (src all-ones, tgt causal).
//
//  - GEMM: 128x64 tile, BK=32, 4 waves (2x2), 4x2 frags/wave, global_load_lds(16B)
//    into k-panel LDS [k/8][row][8] (conflict-free b128 frag reads).
//  - Attention: flash, 128 q/block, 4 waves x 32 q. Swapped QK^T (S^T = mfma(K, Q))
//    -> softmax stats via 2 shfl_xor; P -> LDS b64 repack; V -> XOR-swizzled
//    transposed panels for PV B-operand.
//  - Weights pre-transposed+cast to bf16 [N][K] in one kernel (10 descriptors).

#define D_MODEL 512
#define NHEAD 8
#define DK 64
#define SEQ 2048
#define MTOK 4096
#define DFF 2048

typedef __attribute__((ext_vector_type(8))) short bf16x8;
typedef __attribute__((ext_vector_type(4))) float f32x4;

__device__ __forceinline__ unsigned short f2bf(float x) {  // RTN-even
  unsigned u = __float_as_uint(x);
  u += 0x7FFF + ((u >> 16) & 1);
  return (unsigned short)(u >> 16);
}
__device__ __forceinline__ unsigned pack2(float a, float b) {
  return (unsigned)f2bf(a) | ((unsigned)f2bf(b) << 16);
}
__device__ __forceinline__ void load_lds16(const unsigned short* g, unsigned short* l) {
  __builtin_amdgcn_global_load_lds(
      (const __attribute__((address_space(1))) void*)g,
      (__attribute__((address_space(3))) void*)l, 16, 0, 0);
}

// ---------------------------------------------------------------------------
// Weight prep: fp32 [K][N] -> bf16 [N][K] (transpose + cast), 10 weights.
struct WDesc { const float* src; unsigned short* dst; int K; int N; };
struct WPack { WDesc d[10]; };

__global__ __launch_bounds__(256)
void wprep_kernel(WPack p) {
  const WDesc wd = p.d[blockIdx.y];
  const int ntx = wd.N >> 5;
  const int ntile = (wd.K >> 5) * ntx;
  if ((int)blockIdx.x >= ntile) return;
  const int n0 = (blockIdx.x % ntx) * 32;
  const int k0 = (blockIdx.x / ntx) * 32;
  __shared__ float T[32][33];
  const int tid = threadIdx.x;
  {
    const int r = tid >> 3, c4 = (tid & 7) * 4;
    float4 v = *(const float4*)(wd.src + (long)(k0 + r) * wd.N + n0 + c4);
    T[r][c4] = v.x; T[r][c4 + 1] = v.y; T[r][c4 + 2] = v.z; T[r][c4 + 3] = v.w;
  }
  __syncthreads();
  {
    const int n = tid >> 3, kq = (tid & 7) * 4;
    ushort4 o;
    o.x = f2bf(T[kq + 0][n]); o.y = f2bf(T[kq + 1][n]);
    o.z = f2bf(T[kq + 2][n]); o.w = f2bf(T[kq + 3][n]);
    *(ushort4*)(wd.dst + (long)(n0 + n) * wd.K + k0 + kq) = o;
  }
}

// fp32 -> bf16 cast (8 elems/thread)
__global__ __launch_bounds__(256)
void cast_kernel(const float* __restrict__ s, unsigned short* __restrict__ d, int n8) {
  const int i = blockIdx.x * 256 + threadIdx.x;
  if (i >= n8) return;
  float4 a = *(const float4*)(s + (long)i * 8);
  float4 b = *(const float4*)(s + (long)i * 8 + 4);
  uint4 o;
  o.x = pack2(a.x, a.y); o.y = pack2(a.z, a.w);
  o.z = pack2(b.x, b.y); o.w = pack2(b.z, b.w);
  *(uint4*)(d + (long)i * 8) = o;
}

// ---------------------------------------------------------------------------
// bf16 MFMA GEMM: out = A[M,K] @ Wt[N,K]^T + bias (+res / relu / scale).
// MODE 0: bf16 out, head-split [B,H,S,dk], *scale (Q=0.125). N must be 512.
// MODE 1: fp32 out [M,N], + residual.
// MODE 2: bf16 out [M,N], relu.
template<int MODE>
__global__ __launch_bounds__(256)
void gemm_bf16(const unsigned short* __restrict__ A, const unsigned short* __restrict__ Wt,
               const float* __restrict__ bias, const float* __restrict__ res,
               void* __restrict__ outp, int M, int N, int K, float scale) {
  __shared__ unsigned short As[4096];  // [kg4][m128][8]
  __shared__ unsigned short Bs[2048];  // [kg4][n64][8]
  const int tid = threadIdx.x;
  const int w = tid >> 6, lane = tid & 63, g = lane >> 4, li = lane & 15;
  const int m0 = blockIdx.x * 128, n0 = blockIdx.y * 64;
  const int wm = w >> 1, wn = w & 1;

  f32x4 acc[4][2] = {};
  // A chunks: idx = i*256+tid -> kg=idx>>7, m=idx&127 ; B: idx=tid -> kg=idx>>6, n=idx&63
  const int a0kg = tid >> 7, a0m = tid & 127;
  const int a1kg = (tid + 256) >> 7, a1m = (tid + 256) & 127;
  const int bkg = tid >> 6, bn = tid & 63;
  const unsigned short* Ap0 = A + (long)(m0 + a0m) * K + a0kg * 8;
  const unsigned short* Ap1 = A + (long)(m0 + a1m) * K + a1kg * 8;
  const unsigned short* Bp = Wt + (long)(n0 + bn) * K + bkg * 8;

  for (int k0 = 0; k0 < K; k0 += 32) {
    __syncthreads();
    load_lds16(Ap0 + k0, &As[(w * 64) * 8]);
    load_lds16(Ap1 + k0, &As[(256 + w * 64) * 8]);
    load_lds16(Bp + k0, &Bs[(w * 64) * 8]);
    __syncthreads();
    bf16x8 af[4], bfr[2];
#pragma unroll
    for (int mf = 0; mf < 4; mf++)
      af[mf] = *(const bf16x8*)&As[(g * 128 + wm * 64 + mf * 16 + li) * 8];
#pragma unroll
    for (int nf = 0; nf < 2; nf++)
      bfr[nf] = *(const bf16x8*)&Bs[(g * 64 + wn * 32 + nf * 16 + li) * 8];
#pragma unroll
    for (int mf = 0; mf < 4; mf++)
#pragma unroll
      for (int nf = 0; nf < 2; nf++)
        acc[mf][nf] = __builtin_amdgcn_mfma_f32_16x16x32_bf16(af[mf], bfr[nf], acc[mf][nf], 0, 0, 0);
  }

#pragma unroll
  for (int nf = 0; nf < 2; nf++) {
    const int c = n0 + wn * 32 + nf * 16 + li;
    const float bv = bias[c];
#pragma unroll
    for (int mf = 0; mf < 4; mf++) {
#pragma unroll
      for (int j = 0; j < 4; j++) {
        const int r = m0 + wm * 64 + mf * 16 + g * 4 + j;
        float v = acc[mf][nf][j] + bv;
        if (MODE == 0) {
          v *= scale;
          const int b = r >> 11, s = r & (SEQ - 1), h = c >> 6, d = c & 63;
          ((unsigned short*)outp)[(((long)(b * NHEAD + h)) * SEQ + s) * DK + d] = f2bf(v);
        } else if (MODE == 1) {
          v += res[(long)r * N + c];
          ((float*)outp)[(long)r * N + c] = v;
        } else {
          v = fmaxf(v, 0.f);
          ((unsigned short*)outp)[(long)r * N + c] = f2bf(v);
        }
      }
    }
  }
}

// ---------------------------------------------------------------------------
// Flash attention, bf16 MFMA. Q,K,V bf16 [B,H,S,dk] (Q pre-scaled 1/8).
// Out: AO bf16 [B,S,D_MODEL]. Block: 256 thr, 128 q-rows. grid (S/128, B*H).
template<bool CAUSAL>
__global__ __launch_bounds__(256)
void attn_bf16(const unsigned short* __restrict__ Qg, const unsigned short* __restrict__ Kg,
               const unsigned short* __restrict__ Vg, unsigned short* __restrict__ Og) {
  __shared__ unsigned short Qp[8192];   // [dg8][q128][8]
  __shared__ unsigned short Kp[4096];   // [dg8][k64][8]
  __shared__ unsigned short Vt[4096];   // [sg8][d64^swz][8]
  __shared__ unsigned short Pl[4][2048];  // per-wave [k/8][q32][8]
  const int tid = threadIdx.x;
  const int w = tid >> 6, lane = tid & 63, g = lane >> 4, li = lane & 15;
  const int qb = blockIdx.x, bh = blockIdx.y;
  const int q0 = qb * 128;
  const long base = (long)bh * SEQ * DK;

  // stage Q (1024 chunks of 16B)
#pragma unroll
  for (int i = 0; i < 4; i++) {
    const int idx = i * 256 + tid;
    const int dg = idx >> 7, q = idx & 127;
    load_lds16(Qg + base + (long)(q0 + q) * DK + dg * 8, &Qp[(i * 256 + w * 64) * 8]);
  }
  __syncthreads();
  bf16x8 bq[2][2];
#pragma unroll
  for (int qf = 0; qf < 2; qf++)
#pragma unroll
    for (int ks = 0; ks < 2; ks++)
      bq[qf][ks] = *(const bf16x8*)&Qp[((ks * 4 + g) * 128 + w * 32 + qf * 16 + li) * 8];

  f32x4 oacc[2][4] = {};
  float mrun[2] = {-1e30f, -1e30f};
  float denom[2] = {0.f, 0.f};

  const int vdg = tid >> 5;          // 0..7
  const int vs0 = (tid & 31) * 2;    // even row pair
  const int vsg = vs0 >> 3, vso = vs0 & 7;

  const int ntile = CAUSAL ? (2 * qb + 2) : (SEQ / 64);
  for (int t = 0; t < ntile; t++) {
    const int k0 = t * 64;
    __syncthreads();  // previous tile's Kp/Vt reads complete
    // K DMA (512 chunks)
#pragma unroll
    for (int i = 0; i < 2; i++) {
      const int idx = i * 256 + tid;
      const int dg = idx >> 6, kk = idx & 63;
      load_lds16(Kg + base + (long)(k0 + kk) * DK + dg * 8, &Kp[(i * 256 + w * 64) * 8]);
    }
    // V reg-stage -> swizzled transposed panels
    {
      const unsigned short* vsrc = Vg + base + (long)(k0 + vs0) * DK + vdg * 8;
      uint4 r0 = *(const uint4*)vsrc;
      uint4 r1 = *(const uint4*)(vsrc + DK);
      unsigned short u0[8], u1[8];
      *(uint4*)u0 = r0; *(uint4*)u1 = r1;
#pragma unroll
      for (int e = 0; e < 8; e++) {
        const int d = vdg * 8 + e;
        const int dsw = d ^ (vsg & 7);
        *(unsigned*)&Vt[(vsg * 64 + dsw) * 8 + vso] =
            (unsigned)u0[e] | ((unsigned)u1[e] << 16);
      }
    }
    __syncthreads();

    // S^T = K * Q^T : sacc[kf][qf][j] = S[q = w*32+qf*16+li][k = kf*16+g*4+j]
    f32x4 sacc[4][2] = {};
#pragma unroll
    for (int ks = 0; ks < 2; ks++) {
#pragma unroll
      for (int kf = 0; kf < 4; kf++) {
        bf16x8 ka = *(const bf16x8*)&Kp[((ks * 4 + g) * 64 + kf * 16 + li) * 8];
#pragma unroll
        for (int qf = 0; qf < 2; qf++)
          sacc[kf][qf] = __builtin_amdgcn_mfma_f32_16x16x32_bf16(ka, bq[qf][ks], sacc[kf][qf], 0, 0, 0);
      }
    }
    if (CAUSAL && t >= 2 * qb) {
#pragma unroll
      for (int kf = 0; kf < 4; kf++)
#pragma unroll
        for (int qf = 0; qf < 2; qf++)
#pragma unroll
          for (int j = 0; j < 4; j++) {
            const int kg_ = k0 + kf * 16 + g * 4 + j;
            const int qg_ = q0 + w * 32 + qf * 16 + li;
            if (kg_ > qg_) sacc[kf][qf][j] = -1e30f;
          }
    }
    // online softmax per q (stats across g via xor 16/32)
    float corrv[2];
#pragma unroll
    for (int qf = 0; qf < 2; qf++) {
      float mx = -1e30f;
#pragma unroll
      for (int kf = 0; kf < 4; kf++)
#pragma unroll
        for (int j = 0; j < 4; j++) mx = fmaxf(mx, sacc[kf][qf][j]);
      mx = fmaxf(mx, __shfl_xor(mx, 16, 64));
      mx = fmaxf(mx, __shfl_xor(mx, 32, 64));
      const float mn = fmaxf(mrun[qf], mx);
      const float corr = __expf(mrun[qf] - mn);
      mrun[qf] = mn;
      float ps = 0.f;
#pragma unroll
      for (int kf = 0; kf < 4; kf++)
#pragma unroll
        for (int j = 0; j < 4; j++) {
          const float p = __expf(sacc[kf][qf][j] - mn);
          sacc[kf][qf][j] = p;
          ps += p;
        }
      ps += __shfl_xor(ps, 16, 64);
      ps += __shfl_xor(ps, 32, 64);
      denom[qf] = denom[qf] * corr + ps;
      corrv[qf] = corr;
    }
    // rescale O
#pragma unroll
    for (int mf = 0; mf < 2; mf++)
#pragma unroll
      for (int j = 0; j < 4; j++) {
        const float cf = __shfl(corrv[mf], g * 4 + j, 64);
#pragma unroll
        for (int df = 0; df < 4; df++) oacc[mf][df][j] *= cf;
      }
    // write P^T regs -> Pl[w] as [k/8][q32][k&7]
#pragma unroll
    for (int kf = 0; kf < 4; kf++)
#pragma unroll
      for (int qf = 0; qf < 2; qf++) {
        uint2 pv;
        pv.x = pack2(sacc[kf][qf][0], sacc[kf][qf][1]);
        pv.y = pack2(sacc[kf][qf][2], sacc[kf][qf][3]);
        *(uint2*)&Pl[w][((kf * 2 + (g >> 1)) * 32 + qf * 16 + li) * 8 + (g & 1) * 4] = pv;
      }
    // PV: O += P @ V   (Pl per-wave private; in-wave DS ordering suffices)
#pragma unroll
    for (int ks2 = 0; ks2 < 2; ks2++) {
      const int sg = ks2 * 4 + g;
#pragma unroll
      for (int mf = 0; mf < 2; mf++) {
        bf16x8 pa = *(const bf16x8*)&Pl[w][(sg * 32 + mf * 16 + li) * 8];
#pragma unroll
        for (int df = 0; df < 4; df++) {
          bf16x8 vb = *(const bf16x8*)&Vt[(sg * 64 + ((df * 16 + li) ^ (sg & 7))) * 8];
          oacc[mf][df] = __builtin_amdgcn_mfma_f32_16x16x32_bf16(pa, vb, oacc[mf][df], 0, 0, 0);
        }
      }
    }
  }

  // epilogue: O /= denom, store bf16 into [B,S,D_MODEL]
  const int b = bh >> 3, h = bh & 7;
  float rinv[2] = {1.f / denom[0], 1.f / denom[1]};
#pragma unroll
  for (int mf = 0; mf < 2; mf++)
#pragma unroll
    for (int j = 0; j < 4; j++) {
      const float dj = __shfl(rinv[mf], g * 4 + j, 64);
      const int q = q0 + w * 32 + mf * 16 + g * 4 + j;
#pragma unroll
      for (int df = 0; df < 4; df++) {
        const int col = h * DK + df * 16 + li;
        Og[((long)(b * SEQ + q)) * D_MODEL + col] = f2bf(oacc[mf][df][j] * dj);
      }
    }
}

// ---------------------------------------------------------------------------
// LayerNorm (512). One wave/row. DUAL: also emit bf16 copy.
template<bool DUAL>
__global__ __launch_bounds__(256)
void ln_kernel(const float* __restrict__ x, const float* __restrict__ gam,
               const float* __restrict__ bet, float* __restrict__ out,
               unsigned short* __restrict__ outb) {
  const int row = blockIdx.x * 4 + (threadIdx.x >> 6);
  const int lane = threadIdx.x & 63;
  const float* xr = x + (long)row * D_MODEL;
  float4 v0 = *(const float4*)&xr[lane * 8];
  float4 v1 = *(const float4*)&xr[lane * 8 + 4];
  float xv[8] = {v0.x, v0.y, v0.z, v0.w, v1.x, v1.y, v1.z, v1.w};
  float s = 0.f, s2 = 0.f;
#pragma unroll
  for (int i = 0; i < 8; i++) { s += xv[i]; s2 = fmaf(xv[i], xv[i], s2); }
#pragma unroll
  for (int off = 32; off > 0; off >>= 1) {
    s += __shfl_xor(s, off, 64);
    s2 += __shfl_xor(s2, off, 64);
  }
  const float mu = s * (1.f / D_MODEL);
  const float var = fmaxf(s2 * (1.f / D_MODEL) - mu * mu, 0.f);
  const float rstd = rsqrtf(var + 1e-5f);
  float y[8];
#pragma unroll
  for (int i = 0; i < 8; i++) {
    const int c = lane * 8 + i;
    y[i] = (xv[i] - mu) * rstd * gam[c] + bet[c];
  }
  float* orow = out + (long)row * D_MODEL + lane * 8;
  *(float4*)orow = make_float4(y[0], y[1], y[2], y[3]);
  *(float4*)(orow + 4) = make_float4(y[4], y[5], y[6], y[7]);
  if (DUAL) {
    uint4 o;
    o.x = pack2(y[0], y[1]); o.y = pack2(y[2], y[3]);
    o.z = pack2(y[4], y[5]); o.w = pack2(y[6], y[7]);
    *(uint4*)(outb + (long)row * D_MODEL + lane * 8) = o;
  }
}

// ---------------------------------------------------------------------------
extern "C" void kernel_launch(void* const* d_in, const int* in_sizes, int n_in,
                              void* d_out, int out_size, void* d_ws, size_t ws_size,
                              hipStream_t stream) {
  const float* dec = (const float*)d_in[0];
  const float* enc = (const float*)d_in[1];
  const float* sa_wq = (const float*)d_in[4];
  const float* sa_bq = (const float*)d_in[5];
  const float* sa_wk = (const float*)d_in[6];
  const float* sa_bk = (const float*)d_in[7];
  const float* sa_wv = (const float*)d_in[8];
  const float* sa_bv = (const float*)d_in[9];
  const float* sa_wo = (const float*)d_in[10];
  const float* sa_bo = (const float*)d_in[11];
  const float* ca_wq = (const float*)d_in[12];
  const float* ca_bq = (const float*)d_in[13];
  const float* ca_wk = (const float*)d_in[14];
  const float* ca_bk = (const float*)d_in[15];
  const float* ca_wv = (const float*)d_in[16];
  const float* ca_bv = (const float*)d_in[17];
  const float* ca_wo = (const float*)d_in[18];
  const float* ca_bo = (const float*)d_in[19];
  const float* ffn_w1 = (const float*)d_in[20];
  const float* ffn_b1 = (const float*)d_in[21];
  const float* ffn_w2 = (const float*)d_in[22];
  const float* ffn_b2 = (const float*)d_in[23];
  const float* ln1_g = (const float*)d_in[24];
  const float* ln1_b = (const float*)d_in[25];
  const float* ln2_g = (const float*)d_in[26];
  const float* ln2_b = (const float*)d_in[27];
  const float* ln3_g = (const float*)d_in[28];
  const float* ln3_b = (const float*)d_in[29];

  // ---- workspace (80 MB) ----
  unsigned short* U = (unsigned short*)d_ws;
  unsigned short* wq_t = U + 0;
  unsigned short* wk_t = U + 262144;
  unsigned short* wv_t = U + 524288;
  unsigned short* wo_t = U + 786432;
  unsigned short* cq_t = U + 1048576;
  unsigned short* ck_t = U + 1310720;
  unsigned short* cv_t = U + 1572864;
  unsigned short* co_t = U + 1835008;
  unsigned short* f1_t = U + 2097152;   // [2048][512]
  unsigned short* f2_t = U + 3145728;   // [512][2048]
  unsigned short* dec_bf = U + 4194304;
  unsigned short* enc_bf = U + 6291456;
  unsigned short* Qb  = U + 8388608;
  unsigned short* Kb  = U + 10485760;
  unsigned short* Vb  = U + 12582912;
  unsigned short* AOb = U + 14680064;
  unsigned short* X1b = U + 16777216;
  unsigned short* X2b = U + 18874368;
  unsigned short* MIDb = U + 20971520;  // [4096][2048]
  float* F = (float*)(U + 29360128);
  float* R  = F;
  float* X1 = F + 2097152;
  float* X2 = F + 4194304;

  dim3 blk(256);
  dim3 g512(MTOK / 128, D_MODEL / 64);  // (32, 8)
  dim3 gff1(MTOK / 128, DFF / 64);      // (32, 32)
  dim3 gattn(SEQ / 128, 2 * NHEAD);     // (16, 16)

  // ---- prep: weights + input casts ----
  WPack wp;
  wp.d[0] = {sa_wq, wq_t, D_MODEL, D_MODEL};
  wp.d[1] = {sa_wk, wk_t, D_MODEL, D_MODEL};
  wp.d[2] = {sa_wv, wv_t, D_MODEL, D_MODEL};
  wp.d[3] = {sa_wo, wo_t, D_MODEL, D_MODEL};
  wp.d[4] = {ca_wq, cq_t, D_MODEL, D_MODEL};
  wp.d[5] = {ca_wk, ck_t, D_MODEL, D_MODEL};
  wp.d[6] = {ca_wv, cv_t, D_MODEL, D_MODEL};
  wp.d[7] = {ca_wo, co_t, D_MODEL, D_MODEL};
  wp.d[8] = {ffn_w1, f1_t, D_MODEL, DFF};
  wp.d[9] = {ffn_w2, f2_t, DFF, D_MODEL};
  wprep_kernel<<<dim3(1024, 10), blk, 0, stream>>>(wp);
  cast_kernel<<<1024, blk, 0, stream>>>(dec, dec_bf, MTOK * D_MODEL / 8);
  cast_kernel<<<1024, blk, 0, stream>>>(enc, enc_bf, MTOK * D_MODEL / 8);

  // ---- self-attention ----
  gemm_bf16<0><<<g512, blk, 0, stream>>>(dec_bf, wq_t, sa_bq, nullptr, Qb, MTOK, D_MODEL, D_MODEL, 0.125f);
  gemm_bf16<0><<<g512, blk, 0, stream>>>(dec_bf, wk_t, sa_bk, nullptr, Kb, MTOK, D_MODEL, D_MODEL, 1.f);
  gemm_bf16<0><<<g512, blk, 0, stream>>>(dec_bf, wv_t, sa_bv, nullptr, Vb, MTOK, D_MODEL, D_MODEL, 1.f);
  attn_bf16<true><<<gattn, blk, 0, stream>>>(Qb, Kb, Vb, AOb);
  gemm_bf16<1><<<g512, blk, 0, stream>>>(AOb, wo_t, sa_bo, dec, R, MTOK, D_MODEL, D_MODEL, 1.f);
  ln_kernel<true><<<MTOK / 4, blk, 0, stream>>>(R, ln1_g, ln1_b, X1, X1b);

  // ---- cross-attention ----
  gemm_bf16<0><<<g512, blk, 0, stream>>>(X1b, cq_t, ca_bq, nullptr, Qb, MTOK, D_MODEL, D_MODEL, 0.125f);
  gemm_bf16<0><<<g512, blk, 0, stream>>>(enc_bf, ck_t, ca_bk, nullptr, Kb, MTOK, D_MODEL, D_MODEL, 1.f);
  gemm_bf16<0><<<g512, blk, 0, stream>>>(enc_bf, cv_t, ca_bv, nullptr, Vb, MTOK, D_MODEL, D_MODEL, 1.f);
  attn_bf16<false><<<gattn, blk, 0, stream>>>(Qb, Kb, Vb, AOb);
  gemm_bf16<1><<<g512, blk, 0, stream>>>(AOb, co_t, ca_bo, X1, R, MTOK, D_MODEL, D_MODEL, 1.f);
  ln_kernel<true><<<MTOK / 4, blk, 0, stream>>>(R, ln2_g, ln2_b, X2, X2b);

  // ---- FFN ----
  gemm_bf16<2><<<gff1, blk, 0, stream>>>(X2b, f1_t, ffn_b1, nullptr, MIDb, MTOK, DFF, D_MODEL, 1.f);
  gemm_bf16<1><<<g512, blk, 0, stream>>>(MIDb, f2_t, ffn_b2, X2, R, MTOK, D_MODEL, DFF, 1.f);
  ln_kernel<false><<<MTOK / 4, blk, 0, stream>>>(R, ln3_g, ln3_b, (float*)d_out, nullptr);
}

// Round 4
// 435.021 us; speedup vs baseline: 3.1516x; 1.1511x over previous
//
#include <hip/hip_runtime.h>

// DecoderLayer (eval): SA(causal) -> +res -> LN1 -> CA -> +res -> LN2 -> FFN -> +res -> LN3
// Round-4: occupancy repair.
//  - Attention: flash with KV-split (4 chunks) -> grid (16,16,4)=1024 blocks (4/CU),
//    LDS 32KB (P-buffer aliases dead Q-stage buffer), exp2-domain softmax
//    (0.125*log2e folded into Q projection), fp32 unnormalized partials + LSE combine.
//  - GEMMs: SA QKV fused (N=1536), CA KV fused (N=1024); N=512 GEMMs use BM=64 tiles.
//  - LN stores (mu,rstd); CA-O/FFN2 epilogues recompute LN residual, update R in place
//    (no fp32 X1/X2 buffers -> partials fit ws).

#define D_MODEL 512
#define NHEAD 8
#define DK 64
#define SEQ 2048
#define MTOK 4096
#define DFF 2048

typedef __attribute__((ext_vector_type(8))) short bf16x8;
typedef __attribute__((ext_vector_type(4))) float f32x4;

__device__ __forceinline__ unsigned short f2bf(float x) {  // RTN-even
  unsigned u = __float_as_uint(x);
  u += 0x7FFF + ((u >> 16) & 1);
  return (unsigned short)(u >> 16);
}
__device__ __forceinline__ unsigned pack2(float a, float b) {
  return (unsigned)f2bf(a) | ((unsigned)f2bf(b) << 16);
}
__device__ __forceinline__ void load_lds16(const unsigned short* g, unsigned short* l) {
  __builtin_amdgcn_global_load_lds(
      (const __attribute__((address_space(1))) void*)g,
      (__attribute__((address_space(3))) void*)l, 16, 0, 0);
}

// ---------------------------------------------------------------------------
// Weight prep: fp32 [K][N] -> bf16 [N][K] (transpose + cast). Concat via dst offsets.
struct WDesc { const float* src; unsigned short* dst; int K; int N; };
struct WPack { WDesc d[10]; };

__global__ __launch_bounds__(256)
void wprep_kernel(WPack p) {
  const WDesc wd = p.d[blockIdx.y];
  const int ntx = wd.N >> 5;
  const int ntile = (wd.K >> 5) * ntx;
  if ((int)blockIdx.x >= ntile) return;
  const int n0 = (blockIdx.x % ntx) * 32;
  const int k0 = (blockIdx.x / ntx) * 32;
  __shared__ float T[32][33];
  const int tid = threadIdx.x;
  {
    const int r = tid >> 3, c4 = (tid & 7) * 4;
    float4 v = *(const float4*)(wd.src + (long)(k0 + r) * wd.N + n0 + c4);
    T[r][c4] = v.x; T[r][c4 + 1] = v.y; T[r][c4 + 2] = v.z; T[r][c4 + 3] = v.w;
  }
  __syncthreads();
  {
    const int n = tid >> 3, kq = (tid & 7) * 4;
    ushort4 o;
    o.x = f2bf(T[kq + 0][n]); o.y = f2bf(T[kq + 1][n]);
    o.z = f2bf(T[kq + 2][n]); o.w = f2bf(T[kq + 3][n]);
    *(ushort4*)(wd.dst + (long)(n0 + n) * wd.K + k0 + kq) = o;
  }
}

__global__ __launch_bounds__(256)
void cast_kernel(const float* __restrict__ s, unsigned short* __restrict__ d, int n8) {
  const int i = blockIdx.x * 256 + threadIdx.x;
  if (i >= n8) return;
  float4 a = *(const float4*)(s + (long)i * 8);
  float4 b = *(const float4*)(s + (long)i * 8 + 4);
  uint4 o;
  o.x = pack2(a.x, a.y); o.y = pack2(a.z, a.w);
  o.z = pack2(b.x, b.y); o.w = pack2(b.z, b.w);
  *(uint4*)(d + (long)i * 8) = o;
}

// ---------------------------------------------------------------------------
// bf16 MFMA GEMM, tile BM x 64, BK=32, 4 waves (2x2).
// MODE 0: head-split bf16 out to o{0,1,2} by c>>9, bias b{0,1,2}[c&511], *scale0 on o0.
// MODE 1: fp32 out of = acc + b0[c] + res[r,c].
// MODE 2: bf16 out o0 = relu(acc + b0[c]).
// MODE 3: fp32 out of = acc + b0[c] + LN(res[r,c]; lnm,lnr,lng,lnbt)   (of may alias res).
template<int MODE, int BM>
__global__ __launch_bounds__(256)
void gemm_bf16(const unsigned short* __restrict__ A, const unsigned short* __restrict__ Wt,
               const float* __restrict__ b0, const float* __restrict__ b1,
               const float* __restrict__ b2, const float* res,
               const float* __restrict__ lnm, const float* __restrict__ lnr,
               const float* __restrict__ lng, const float* __restrict__ lnbt,
               unsigned short* __restrict__ o0, unsigned short* __restrict__ o1,
               unsigned short* __restrict__ o2, float* of,
               int M, int N, int K, float scale0) {
  constexpr int MF = BM / 32;
  __shared__ unsigned short As[BM * 32];  // [kg4][mBM][8]
  __shared__ unsigned short Bs[2048];     // [kg4][n64][8]
  const int tid = threadIdx.x;
  const int w = tid >> 6, lane = tid & 63, g = lane >> 4, li = lane & 15;
  const int m0 = blockIdx.x * BM, n0 = blockIdx.y * 64;
  const int wm = w >> 1, wn = w & 1;

  f32x4 acc[MF][2] = {};
  const int bkg = tid >> 6, bn = tid & 63;
  const unsigned short* Bp = Wt + (long)(n0 + bn) * K + bkg * 8;

  const unsigned short* Ap0;
  const unsigned short* Ap1 = nullptr;
  if constexpr (BM == 128) {
    Ap0 = A + (long)(m0 + (tid & 127)) * K + (tid >> 7) * 8;
    Ap1 = A + (long)(m0 + (tid & 127)) * K + ((tid >> 7) + 2) * 8;
  } else {
    Ap0 = A + (long)(m0 + (tid & 63)) * K + (tid >> 6) * 8;
  }

  for (int k0 = 0; k0 < K; k0 += 32) {
    __syncthreads();
    load_lds16(Ap0 + k0, &As[(w * 64) * 8]);
    if constexpr (BM == 128) load_lds16(Ap1 + k0, &As[(256 + w * 64) * 8]);
    load_lds16(Bp + k0, &Bs[(w * 64) * 8]);
    __syncthreads();
    bf16x8 af[MF], bfr[2];
#pragma unroll
    for (int mf = 0; mf < MF; mf++)
      af[mf] = *(const bf16x8*)&As[(g * BM + wm * (BM / 2) + mf * 16 + li) * 8];
#pragma unroll
    for (int nf = 0; nf < 2; nf++)
      bfr[nf] = *(const bf16x8*)&Bs[(g * 64 + wn * 32 + nf * 16 + li) * 8];
#pragma unroll
    for (int mf = 0; mf < MF; mf++)
#pragma unroll
      for (int nf = 0; nf < 2; nf++)
        acc[mf][nf] = __builtin_amdgcn_mfma_f32_16x16x32_bf16(af[mf], bfr[nf], acc[mf][nf], 0, 0, 0);
  }

#pragma unroll
  for (int nf = 0; nf < 2; nf++) {
    const int c = n0 + wn * 32 + nf * 16 + li;
    float bias, scl = 1.f;
    unsigned short* hdst = nullptr;
    float lngv = 0.f, lnbv = 0.f;
    if constexpr (MODE == 0) {
      const int which = c >> 9;
      bias = (which == 0 ? b0 : (which == 1 ? b1 : b2))[c & 511];
      if (which == 0) scl = scale0;
      hdst = which == 0 ? o0 : (which == 1 ? o1 : o2);
    } else {
      bias = b0[c];
      if constexpr (MODE == 3) { lngv = lng[c]; lnbv = lnbt[c]; }
    }
#pragma unroll
    for (int mf = 0; mf < MF; mf++) {
#pragma unroll
      for (int j = 0; j < 4; j++) {
        const int r = m0 + wm * (BM / 2) + mf * 16 + g * 4 + j;
        float v = acc[mf][nf][j] + bias;
        if constexpr (MODE == 0) {
          v *= scl;
          const int b = r >> 11, s = r & (SEQ - 1), h = (c >> 6) & 7, d = c & 63;
          hdst[(((long)(b * NHEAD + h)) * SEQ + s) * DK + d] = f2bf(v);
        } else if constexpr (MODE == 1) {
          v += res[(long)r * N + c];
          of[(long)r * N + c] = v;
        } else if constexpr (MODE == 2) {
          o0[(long)r * N + c] = f2bf(fmaxf(v, 0.f));
        } else {
          const float xr = res[(long)r * N + c];
          v += (xr - lnm[r]) * lnr[r] * lngv + lnbv;
          of[(long)r * N + c] = v;
        }
      }
    }
  }
}

// ---------------------------------------------------------------------------
// Flash attention chunk, bf16 MFMA. Q pre-scaled by 0.125*log2e (exp2 domain).
// Grid (SEQ/128, B*NHEAD, 4). Writes unnormalized fp32 O + (m,l) per chunk.
template<bool CAUSAL>
__global__ __launch_bounds__(256)
void attn_bf16(const unsigned short* __restrict__ Qg, const unsigned short* __restrict__ Kg,
               const unsigned short* __restrict__ Vg, float* __restrict__ Opart,
               float* __restrict__ Mst, float* __restrict__ Lst) {
  __shared__ unsigned short SM[16384];   // 32KB
  unsigned short* const Qp = SM;         // [dg8][q128][8]  (dead after bq load)
  unsigned short* const Kp = SM + 8192;  // [dg8][k64][8]
  unsigned short* const Vt = SM + 12288; // [sg8][d64^swz][8]
  const int tid = threadIdx.x;
  const int w = tid >> 6, lane = tid & 63, g = lane >> 4, li = lane & 15;
  const int qb = blockIdx.x, bh = blockIdx.y, ck = blockIdx.z;
  const int q0 = qb * 128;
  const long base = (long)bh * SEQ * DK;
  unsigned short* const Pl = SM + w * 2048;  // aliases Qp region (per-wave)

#pragma unroll
  for (int i = 0; i < 4; i++) {
    const int idx = i * 256 + tid;
    const int dg = idx >> 7, q = idx & 127;
    load_lds16(Qg + base + (long)(q0 + q) * DK + dg * 8, &Qp[(i * 256 + w * 64) * 8]);
  }
  __syncthreads();
  bf16x8 bq[2][2];
#pragma unroll
  for (int qf = 0; qf < 2; qf++)
#pragma unroll
    for (int ks = 0; ks < 2; ks++)
      bq[qf][ks] = *(const bf16x8*)&Qp[((ks * 4 + g) * 128 + w * 32 + qf * 16 + li) * 8];

  f32x4 oacc[2][4] = {};
  float mrun[2] = {-1e30f, -1e30f};
  float denom[2] = {0.f, 0.f};

  const int vdg = tid >> 5;
  const int vs0 = (tid & 31) * 2;
  const int vsg = vs0 >> 3, vso = vs0 & 7;

  const int tbeg = CAUSAL ? ck : ck * 8;
  const int tend = CAUSAL ? (2 * qb + 2) : (ck * 8 + 8);
  const int tstep = CAUSAL ? 4 : 1;
  for (int t = tbeg; t < tend; t += tstep) {
    const int k0 = t * 64;
    __syncthreads();
#pragma unroll
    for (int i = 0; i < 2; i++) {
      const int idx = i * 256 + tid;
      const int dg = idx >> 6, kk = idx & 63;
      load_lds16(Kg + base + (long)(k0 + kk) * DK + dg * 8, &Kp[(i * 256 + w * 64) * 8]);
    }
    {
      const unsigned short* vsrc = Vg + base + (long)(k0 + vs0) * DK + vdg * 8;
      uint4 r0 = *(const uint4*)vsrc;
      uint4 r1 = *(const uint4*)(vsrc + DK);
      unsigned short u0[8], u1[8];
      *(uint4*)u0 = r0; *(uint4*)u1 = r1;
#pragma unroll
      for (int e = 0; e < 8; e++) {
        const int d = vdg * 8 + e;
        const int dsw = d ^ (vsg & 7);
        *(unsigned*)&Vt[(vsg * 64 + dsw) * 8 + vso] =
            (unsigned)u0[e] | ((unsigned)u1[e] << 16);
      }
    }
    __syncthreads();

    // S^T = K * Q^T (exp2 domain; Q pre-scaled)
    f32x4 sacc[4][2] = {};
#pragma unroll
    for (int ks = 0; ks < 2; ks++) {
#pragma unroll
      for (int kf = 0; kf < 4; kf++) {
        bf16x8 ka = *(const bf16x8*)&Kp[((ks * 4 + g) * 64 + kf * 16 + li) * 8];
#pragma unroll
        for (int qf = 0; qf < 2; qf++)
          sacc[kf][qf] = __builtin_amdgcn_mfma_f32_16x16x32_bf16(ka, bq[qf][ks], sacc[kf][qf], 0, 0, 0);
      }
    }
    if (CAUSAL && t >= 2 * qb) {
#pragma unroll
      for (int kf = 0; kf < 4; kf++)
#pragma unroll
        for (int qf = 0; qf < 2; qf++)
#pragma unroll
          for (int j = 0; j < 4; j++) {
            const int kg_ = k0 + kf * 16 + g * 4 + j;
            const int qg_ = q0 + w * 32 + qf * 16 + li;
            if (kg_ > qg_) sacc[kf][qf][j] = -1e30f;
          }
    }
    float corrv[2];
#pragma unroll
    for (int qf = 0; qf < 2; qf++) {
      float mx = -1e30f;
#pragma unroll
      for (int kf = 0; kf < 4; kf++)
#pragma unroll
        for (int j = 0; j < 4; j++) mx = fmaxf(mx, sacc[kf][qf][j]);
      mx = fmaxf(mx, __shfl_xor(mx, 16, 64));
      mx = fmaxf(mx, __shfl_xor(mx, 32, 64));
      const float mn = fmaxf(mrun[qf], mx);
      const float corr = exp2f(mrun[qf] - mn);
      mrun[qf] = mn;
      float ps = 0.f;
#pragma unroll
      for (int kf = 0; kf < 4; kf++)
#pragma unroll
        for (int j = 0; j < 4; j++) {
          const float p = exp2f(sacc[kf][qf][j] - mn);
          sacc[kf][qf][j] = p;
          ps += p;
        }
      ps += __shfl_xor(ps, 16, 64);
      ps += __shfl_xor(ps, 32, 64);
      denom[qf] = denom[qf] * corr + ps;
      corrv[qf] = corr;
    }
#pragma unroll
    for (int mf = 0; mf < 2; mf++)
#pragma unroll
      for (int j = 0; j < 4; j++) {
        const float cf = __shfl(corrv[mf], g * 4 + j, 64);
#pragma unroll
        for (int df = 0; df < 4; df++) oacc[mf][df][j] *= cf;
      }
#pragma unroll
    for (int kf = 0; kf < 4; kf++)
#pragma unroll
      for (int qf = 0; qf < 2; qf++) {
        uint2 pv;
        pv.x = pack2(sacc[kf][qf][0], sacc[kf][qf][1]);
        pv.y = pack2(sacc[kf][qf][2], sacc[kf][qf][3]);
        *(uint2*)&Pl[((kf * 2 + (g >> 1)) * 32 + qf * 16 + li) * 8 + (g & 1) * 4] = pv;
      }
#pragma unroll
    for (int ks2 = 0; ks2 < 2; ks2++) {
      const int sg = ks2 * 4 + g;
#pragma unroll
      for (int mf = 0; mf < 2; mf++) {
        bf16x8 pa = *(const bf16x8*)&Pl[(sg * 32 + mf * 16 + li) * 8];
#pragma unroll
        for (int df = 0; df < 4; df++) {
          bf16x8 vb = *(const bf16x8*)&Vt[(sg * 64 + ((df * 16 + li) ^ (sg & 7))) * 8];
          oacc[mf][df] = __builtin_amdgcn_mfma_f32_16x16x32_bf16(pa, vb, oacc[mf][df], 0, 0, 0);
        }
      }
    }
  }

  // unnormalized partial + stats
  const long pbase = (long)(ck * 16 + bh) * SEQ;
  if (g == 0) {
#pragma unroll
    for (int qf = 0; qf < 2; qf++) {
      const int q = q0 + w * 32 + qf * 16 + li;
      Mst[pbase + q] = mrun[qf];
      Lst[pbase + q] = denom[qf];
    }
  }
#pragma unroll
  for (int mf = 0; mf < 2; mf++)
#pragma unroll
    for (int j = 0; j < 4; j++) {
      const int q = q0 + w * 32 + mf * 16 + g * 4 + j;
      float* op = Opart + (pbase + q) * 64;
#pragma unroll
      for (int df = 0; df < 4; df++) op[df * 16 + li] = oacc[mf][df][j];
    }
}

// ---------------------------------------------------------------------------
// LSE combine over 4 chunks -> AOb bf16 [B,S,D_MODEL]. One wave per q row.
__global__ __launch_bounds__(256)
void combine_kernel(const float* __restrict__ Opart, const float* __restrict__ Mst,
                    const float* __restrict__ Lst, unsigned short* __restrict__ AOb) {
  const int row = blockIdx.x * 4 + (threadIdx.x >> 6);  // bh*SEQ + q
  const int lane = threadIdx.x & 63;
  const int bh = row >> 11, q = row & (SEQ - 1);
  float m[4], l[4], mstar = -1e30f;
#pragma unroll
  for (int c = 0; c < 4; c++) {
    m[c] = Mst[((long)c * 16 + bh) * SEQ + q];
    l[c] = Lst[((long)c * 16 + bh) * SEQ + q];
    mstar = fmaxf(mstar, m[c]);
  }
  float den = 0.f, o = 0.f;
#pragma unroll
  for (int c = 0; c < 4; c++) {
    const float wgt = exp2f(m[c] - mstar);
    den += wgt * l[c];
    o += wgt * Opart[(((long)c * 16 + bh) * SEQ + q) * 64 + lane];
  }
  const int b = bh >> 3, h = bh & 7;
  AOb[((long)(b * SEQ + q)) * D_MODEL + h * DK + lane] = f2bf(o / den);
}

// ---------------------------------------------------------------------------
// LayerNorm (512). V0: bf16 out + (mu,rstd) stats. V1: fp32 out.
template<int V>
__global__ __launch_bounds__(256)
void ln_kernel(const float* __restrict__ x, const float* __restrict__ gam,
               const float* __restrict__ bet, float* __restrict__ outf,
               unsigned short* __restrict__ outb, float* __restrict__ mu_s,
               float* __restrict__ rs_s) {
  const int row = blockIdx.x * 4 + (threadIdx.x >> 6);
  const int lane = threadIdx.x & 63;
  const float* xr = x + (long)row * D_MODEL;
  float4 v0 = *(const float4*)&xr[lane * 8];
  float4 v1 = *(const float4*)&xr[lane * 8 + 4];
  float xv[8] = {v0.x, v0.y, v0.z, v0.w, v1.x, v1.y, v1.z, v1.w};
  float s = 0.f, s2 = 0.f;
#pragma unroll
  for (int i = 0; i < 8; i++) { s += xv[i]; s2 = fmaf(xv[i], xv[i], s2); }
#pragma unroll
  for (int off = 32; off > 0; off >>= 1) {
    s += __shfl_xor(s, off, 64);
    s2 += __shfl_xor(s2, off, 64);
  }
  const float mu = s * (1.f / D_MODEL);
  const float var = fmaxf(s2 * (1.f / D_MODEL) - mu * mu, 0.f);
  const float rstd = rsqrtf(var + 1e-5f);
  float y[8];
#pragma unroll
  for (int i = 0; i < 8; i++) {
    const int c = lane * 8 + i;
    y[i] = (xv[i] - mu) * rstd * gam[c] + bet[c];
  }
  if constexpr (V == 0) {
    uint4 o;
    o.x = pack2(y[0], y[1]); o.y = pack2(y[2], y[3]);
    o.z = pack2(y[4], y[5]); o.w = pack2(y[6], y[7]);
    *(uint4*)(outb + (long)row * D_MODEL + lane * 8) = o;
    if (lane == 0) { mu_s[row] = mu; rs_s[row] = rstd; }
  } else {
    float* orow = outf + (long)row * D_MODEL + lane * 8;
    *(float4*)orow = make_float4(y[0], y[1], y[2], y[3]);
    *(float4*)(orow + 4) = make_float4(y[4], y[5], y[6], y[7]);
  }
}

// ---------------------------------------------------------------------------
extern "C" void kernel_launch(void* const* d_in, const int* in_sizes, int n_in,
                              void* d_out, int out_size, void* d_ws, size_t ws_size,
                              hipStream_t stream) {
  const float* dec = (const float*)d_in[0];
  const float* enc = (const float*)d_in[1];
  const float* sa_wq = (const float*)d_in[4];
  const float* sa_bq = (const float*)d_in[5];
  const float* sa_wk = (const float*)d_in[6];
  const float* sa_bk = (const float*)d_in[7];
  const float* sa_wv = (const float*)d_in[8];
  const float* sa_bv = (const float*)d_in[9];
  const float* sa_wo = (const float*)d_in[10];
  const float* sa_bo = (const float*)d_in[11];
  const float* ca_wq = (const float*)d_in[12];
  const float* ca_bq = (const float*)d_in[13];
  const float* ca_wk = (const float*)d_in[14];
  const float* ca_bk = (const float*)d_in[15];
  const float* ca_wv = (const float*)d_in[16];
  const float* ca_bv = (const float*)d_in[17];
  const float* ca_wo = (const float*)d_in[18];
  const float* ca_bo = (const float*)d_in[19];
  const float* ffn_w1 = (const float*)d_in[20];
  const float* ffn_b1 = (const float*)d_in[21];
  const float* ffn_w2 = (const float*)d_in[22];
  const float* ffn_b2 = (const float*)d_in[23];
  const float* ln1_g = (const float*)d_in[24];
  const float* ln1_b = (const float*)d_in[25];
  const float* ln2_g = (const float*)d_in[26];
  const float* ln2_b = (const float*)d_in[27];
  const float* ln3_g = (const float*)d_in[28];
  const float* ln3_b = (const float*)d_in[29];

  // ---- workspace layout (~77 MiB) ----
  char* wsb = (char*)d_ws;
  // arena [0, 34603008): dec_bf (phase 1-2) / Opart+stats (attn) / MIDb (FFN)
  unsigned short* dec_bf = (unsigned short*)wsb;
  float* Opart = (float*)wsb;                        // 4*16*2048*64 f32 = 33.55MB
  float* Mst = (float*)(wsb + 33554432);
  float* Lst = (float*)(wsb + 34078720);
  unsigned short* MIDb = (unsigned short*)wsb;       // [4096][2048] bf16 (FFN phase)
  size_t off = 34603008;
  unsigned short* qkv_t = (unsigned short*)(wsb + off); off += 1572864;  // [1536][512]
  unsigned short* wo_t  = (unsigned short*)(wsb + off); off += 524288;
  unsigned short* cq_t  = (unsigned short*)(wsb + off); off += 524288;
  unsigned short* ckv_t = (unsigned short*)(wsb + off); off += 1048576;  // [1024][512]
  unsigned short* co_t  = (unsigned short*)(wsb + off); off += 524288;
  unsigned short* f1_t  = (unsigned short*)(wsb + off); off += 2097152;  // [2048][512]
  unsigned short* f2_t  = (unsigned short*)(wsb + off); off += 2097152;  // [512][2048]
  unsigned short* enc_bf = (unsigned short*)(wsb + off); off += 4194304;
  unsigned short* Qb  = (unsigned short*)(wsb + off); off += 4194304;
  unsigned short* Kb  = (unsigned short*)(wsb + off); off += 4194304;
  unsigned short* Vb  = (unsigned short*)(wsb + off); off += 4194304;
  unsigned short* AOb = (unsigned short*)(wsb + off); off += 4194304;
  unsigned short* X1b = (unsigned short*)(wsb + off); off += 4194304;
  unsigned short* X2b = (unsigned short*)(wsb + off); off += 4194304;
  float* R   = (float*)(wsb + off); off += 8388608;
  float* mu1 = (float*)(wsb + off); off += 16384;
  float* rs1 = (float*)(wsb + off); off += 16384;
  float* mu2 = (float*)(wsb + off); off += 16384;
  float* rs2 = (float*)(wsb + off); off += 16384;

  dim3 blk(256);
  const float QS = 0.125f * 1.44269504f;  // 1/sqrt(dk) * log2(e)  (exp2-domain softmax)

  // ---- prep ----
  WPack wp;
  wp.d[0] = {sa_wq, qkv_t, 512, 512};
  wp.d[1] = {sa_wk, qkv_t + 262144, 512, 512};
  wp.d[2] = {sa_wv, qkv_t + 524288, 512, 512};
  wp.d[3] = {sa_wo, wo_t, 512, 512};
  wp.d[4] = {ca_wq, cq_t, 512, 512};
  wp.d[5] = {ca_wk, ckv_t, 512, 512};
  wp.d[6] = {ca_wv, ckv_t + 262144, 512, 512};
  wp.d[7] = {ca_wo, co_t, 512, 512};
  wp.d[8] = {ffn_w1, f1_t, 512, 2048};
  wp.d[9] = {ffn_w2, f2_t, 2048, 512};
  wprep_kernel<<<dim3(1024, 10), blk, 0, stream>>>(wp);
  cast_kernel<<<1024, blk, 0, stream>>>(dec, dec_bf, 262144);
  cast_kernel<<<1024, blk, 0, stream>>>(enc, enc_bf, 262144);

  // ---- self-attention ----
  gemm_bf16<0, 128><<<dim3(32, 24), blk, 0, stream>>>(dec_bf, qkv_t, sa_bq, sa_bk, sa_bv,
      nullptr, nullptr, nullptr, nullptr, nullptr, Qb, Kb, Vb, nullptr, MTOK, 1536, 512, QS);
  attn_bf16<true><<<dim3(16, 16, 4), blk, 0, stream>>>(Qb, Kb, Vb, Opart, Mst, Lst);
  combine_kernel<<<8192, blk, 0, stream>>>(Opart, Mst, Lst, AOb);
  gemm_bf16<1, 64><<<dim3(64, 8), blk, 0, stream>>>(AOb, wo_t, sa_bo, nullptr, nullptr,
      dec, nullptr, nullptr, nullptr, nullptr, nullptr, nullptr, nullptr, R, MTOK, 512, 512, 1.f);
  ln_kernel<0><<<1024, blk, 0, stream>>>(R, ln1_g, ln1_b, nullptr, X1b, mu1, rs1);

  // ---- cross-attention ----
  gemm_bf16<0, 64><<<dim3(64, 8), blk, 0, stream>>>(X1b, cq_t, ca_bq, nullptr, nullptr,
      nullptr, nullptr, nullptr, nullptr, nullptr, Qb, nullptr, nullptr, nullptr, MTOK, 512, 512, QS);
  gemm_bf16<0, 128><<<dim3(32, 16), blk, 0, stream>>>(enc_bf, ckv_t, ca_bk, ca_bv, nullptr,
      nullptr, nullptr, nullptr, nullptr, nullptr, Kb, Vb, nullptr, nullptr, MTOK, 1024, 512, 1.f);
  attn_bf16<false><<<dim3(16, 16, 4), blk, 0, stream>>>(Qb, Kb, Vb, Opart, Mst, Lst);
  combine_kernel<<<8192, blk, 0, stream>>>(Opart, Mst, Lst, AOb);
  gemm_bf16<3, 64><<<dim3(64, 8), blk, 0, stream>>>(AOb, co_t, ca_bo, nullptr, nullptr,
      R, mu1, rs1, ln1_g, ln1_b, nullptr, nullptr, nullptr, R, MTOK, 512, 512, 1.f);
  ln_kernel<0><<<1024, blk, 0, stream>>>(R, ln2_g, ln2_b, nullptr, X2b, mu2, rs2);

  // ---- FFN ----
  gemm_bf16<2, 128><<<dim3(32, 32), blk, 0, stream>>>(X2b, f1_t, ffn_b1, nullptr, nullptr,
      nullptr, nullptr, nullptr, nullptr, nullptr, MIDb, nullptr, nullptr, nullptr, MTOK, 2048, 512, 1.f);
  gemm_bf16<3, 64><<<dim3(64, 8), blk, 0, stream>>>(MIDb, f2_t, ffn_b2, nullptr, nullptr,
      R, mu2, rs2, ln2_g, ln2_b, nullptr, nullptr, nullptr, R, MTOK, 512, 2048, 1.f);
  ln_kernel<1><<<1024, blk, 0, stream>>>(R, ln3_g, ln3_b, (float*)d_out, nullptr, nullptr, nullptr);
}